// Round 7
// baseline (490.126 us; speedup 1.0000x reference)
//
#include <hip/hip_runtime.h>

#define HID 1024
#define ADP 256
#define MB  32

typedef short s16x8 __attribute__((ext_vector_type(8)));
typedef unsigned short u16x8 __attribute__((ext_vector_type(8)));
typedef float f32x4 __attribute__((ext_vector_type(4)));

__device__ __forceinline__ unsigned short f2bf(float f) {
    union { float f; unsigned int u; } v; v.f = f;
    unsigned int r = v.u + 0x7fffu + ((v.u >> 16) & 1u);   // round-to-nearest-even
    return (unsigned short)(r >> 16);
}

__device__ __forceinline__ float bf2f(unsigned short u) {
    union { unsigned int u; float f; } v; v.u = ((unsigned int)u) << 16;
    return v.f;
}

__device__ __forceinline__ float gelu_new_f(float x) {
    float t = 0.7978845608028654f * x * (1.0f + 0.044715f * x * x);
    t = fminf(fmaxf(t, -15.f), 15.f);
    float e = __expf(-2.0f * t);
    float th = (1.0f - e) / (1.0f + e);
    return 0.5f * x * (1.0f + th);
}

// Single prep kernel:
//   blocks 0..127   : pack wd [1024][256] -> WdP fragment tiles (lnw folded)
//   blocks 128..255 : pack wu [256][1024] -> WuP fragment tiles
//   block 256       : svec/tvec correction vectors (coalesced over columns)
// Tile (nti,kti): 1KB, offset (q*16+l15)*8+e = W[kti*32+q*8+e][nti*16+l15]*scale.
__global__ __launch_bounds__(256)
void prep(const float* __restrict__ wd, const float* __restrict__ wu,
          const float* __restrict__ lnw, const float* __restrict__ lnb,
          const float* __restrict__ bdn,
          unsigned short* __restrict__ WdP, unsigned short* __restrict__ WuP,
          float* __restrict__ svec, float* __restrict__ tvec)
{
    __shared__ unsigned short sh[32][72];
    const int b = blockIdx.x, t = threadIdx.x;
    if (b < 256) {
        const float* in; unsigned short* outp; const float* scale; int K, N, kb, nb;
        if (b < 128) { in = wd; outp = WdP; scale = lnw; K = HID; N = ADP; kb = b & 31; nb = b >> 5; }
        else { int i = b - 128; in = wu; outp = WuP; scale = nullptr; K = ADP; N = HID; kb = i & 7; nb = i >> 3; }
        const int k0 = kb * 32, n0 = nb * 64;
        const int r = t >> 3, cg = t & 7;
        const float* src = in + (size_t)(k0 + r) * N + n0 + cg * 8;
        float sc = scale ? scale[k0 + r] : 1.0f;
        f32x4 v0 = *(const f32x4*)(src);
        f32x4 v1 = *(const f32x4*)(src + 4);
        #pragma unroll
        for (int e = 0; e < 4; ++e) {
            sh[r][cg * 8 + e]     = f2bf(sc * v0[e]);
            sh[r][cg * 8 + 4 + e] = f2bf(sc * v1[e]);
        }
        __syncthreads();
        int tile = t >> 6, l = t & 63, q = l >> 4, l15 = l & 15;
        u16x8 o;
        #pragma unroll
        for (int e = 0; e < 8; ++e)
            o[e] = sh[q * 8 + e][tile * 16 + l15];
        size_t tid_g = (size_t)(nb * 4 + tile) * (K / 32) + kb;
        *(u16x8*)(outp + tid_g * 512 + (size_t)l * 8) = o;
    } else {
        // corr: thread t = column a; coalesced row-major reads of wd
        float sv = 0.f, tv = 0.f;
        #pragma unroll 8
        for (int h = 0; h < HID; ++h) {
            float w = wd[(size_t)h * ADP + t];
            sv += bf2f(f2bf(lnw[h] * w));
            tv += lnb[h] * w;
        }
        svec[t] = sv;
        tvec[t] = bdn[t] + tv;
    }
}

__global__ __launch_bounds__(512, 4)
void adapter_fused(const float* __restrict__ x,
                   const float* __restrict__ bup,
                   const float* __restrict__ svec, const float* __restrict__ tvec,
                   const unsigned short* __restrict__ WdP,   // packed [16 nti][32 kti]
                   const unsigned short* __restrict__ WuP,   // packed [64 nti][8 kti]
                   float* __restrict__ out)
{
    __shared__ unsigned short a_h[2][MB][264];  // double-buffered x chunk / h
    __shared__ float ep[8][16][68];             // per-wave epilogue staging (16x64)
    __shared__ float stats_part[MB][16];        // per-wave partial sums (s1,s2 interleaved)
    __shared__ float stats[MB][2];              // mean, rstd
    __shared__ float sv_s[ADP], tv_s[ADP];

    const int tid  = threadIdx.x;
    const int wv   = tid >> 6;                 // 8 waves
    const int lane = tid & 63;
    const int q    = lane >> 4;
    const int l15  = lane & 15;
    const long row0 = (long)blockIdx.x * MB;

    if (tid < ADP) { sv_s[tid] = svec[tid]; tv_s[tid] = tvec[tid]; }

    // ---- register slab: wave wv owns cols [wv*128, wv*128+128) of all 32 rows ----
    const int rowl = lane & 31;                // this lane's row
    const int half = lane >> 5;                // 0/1: which 64-col half of the slab
    const int gcol = wv * 128 + half * 64;     // lane's first global column

    f32x4 xreg[16];                            // 64 floats of x (fp32), 64 VGPRs
    {
        const f32x4* xr = (const f32x4*)(x + (row0 + rowl) * HID + gcol);
        #pragma unroll
        for (int i = 0; i < 16; ++i)
            xreg[i] = __builtin_nontemporal_load(&xr[i]);
    }

    f32x4 c1[2][2];
    #pragma unroll
    for (int a = 0; a < 2; ++a)
        #pragma unroll
        for (int bb = 0; bb < 2; ++bb)
            c1[a][bb] = (f32x4){0.f, 0.f, 0.f, 0.f};

    // stage this wave's slab (bf16) into a_h[buf] chunk (kc = wv>>1) + LN partial sums
    const int colb = (wv & 1) * 128 + half * 64;   // column offset within the 256-col chunk
    auto stage = [&](int buf) {
        float s1 = 0.f, s2 = 0.f;
        #pragma unroll
        for (int i = 0; i < 16; ++i) {
            f32x4 v = xreg[i];
            s1 += v[0] + v[1] + v[2] + v[3];
            s2 += v[0] * v[0] + v[1] * v[1] + v[2] * v[2] + v[3] * v[3];
            ushort4 o;
            o.x = f2bf(v[0]); o.y = f2bf(v[1]); o.z = f2bf(v[2]); o.w = f2bf(v[3]);
            *(ushort4*)&a_h[buf][rowl][colb + i * 4] = o;
        }
        s1 += __shfl_xor(s1, 32);
        s2 += __shfl_xor(s2, 32);
        if (lane < 32) {
            stats_part[rowl][wv * 2]     = s1;
            stats_part[rowl][wv * 2 + 1] = s2;
        }
    };

    if (wv < 2) stage(0);
    __syncthreads();

    // ---- GEMM1: c1 += bf16(x) * WdP, K-chunked with dbuf; owners stage next chunk ----
    for (int kc = 0; kc < 4; ++kc) {
        if (kc < 3 && (wv >> 1) == kc + 1) stage((kc + 1) & 1);
        const int buf = kc & 1;
        #pragma unroll
        for (int ks = 0; ks < 8; ++ks) {
            int kof = ks * 32 + q * 8;
            s16x8 af[2], bfr[2];
            af[0] = *(const s16x8*)&a_h[buf][l15][kof];
            af[1] = *(const s16x8*)&a_h[buf][16 + l15][kof];
            #pragma unroll
            for (int nt = 0; nt < 2; ++nt)
                bfr[nt] = *(const s16x8*)&WdP[(((size_t)(wv * 2 + nt) * 32) + kc * 8 + ks) * 512 + lane * 8];
            #pragma unroll
            for (int mt = 0; mt < 2; ++mt)
                #pragma unroll
                for (int nt = 0; nt < 2; ++nt)
                    c1[mt][nt] = __builtin_amdgcn_mfma_f32_16x16x32_bf16(af[mt], bfr[nt], c1[mt][nt], 0, 0, 0);
        }
        __syncthreads();
    }

    // ---- finalize LN statistics (reduce 8 per-wave partials per row) ----
    if (tid < 32) {
        float s1 = 0.f, s2 = 0.f;
        #pragma unroll
        for (int w = 0; w < 8; ++w) {
            s1 += stats_part[tid][w * 2];
            s2 += stats_part[tid][w * 2 + 1];
        }
        float mean = s1 * (1.f / HID);
        float var  = s2 * (1.f / HID) - mean * mean;
        stats[tid][0] = mean;
        stats[tid][1] = rsqrtf(var + 1e-5f);
    }
    __syncthreads();

    // ---- LN correction + gelu -> bf16 h in a_h[0] (viewed [32][264], 256 cols used) ----
    #pragma unroll
    for (int mt = 0; mt < 2; ++mt)
        #pragma unroll
        for (int nt = 0; nt < 2; ++nt) {
            int a = wv * 32 + nt * 16 + l15;
            float sv = sv_s[a], tv = tv_s[a];
            #pragma unroll
            for (int rr = 0; rr < 4; ++rr) {
                int m = mt * 16 + q * 4 + rr;
                float mean = stats[m][0], rstd = stats[m][1];
                float c = rstd * (c1[mt][nt][rr] - mean * sv) + tv;
                a_h[0][m][a] = f2bf(gelu_new_f(c));
            }
        }
    __syncthreads();

    // ---- GEMM2 + epilogue: wave wv produces cols [wv*128, +128) = its x slab ----
    for (int ncc = 0; ncc < 2; ++ncc) {
        const int cb = wv * 128 + ncc * 64;
        f32x4 c2[2][4];
        #pragma unroll
        for (int a = 0; a < 2; ++a)
            #pragma unroll
            for (int bb = 0; bb < 4; ++bb)
                c2[a][bb] = (f32x4){0.f, 0.f, 0.f, 0.f};
        #pragma unroll
        for (int ks = 0; ks < 8; ++ks) {
            int kof = ks * 32 + q * 8;
            s16x8 af[2], bfr[4];
            af[0] = *(const s16x8*)&a_h[0][l15][kof];
            af[1] = *(const s16x8*)&a_h[0][16 + l15][kof];
            #pragma unroll
            for (int nt = 0; nt < 4; ++nt)
                bfr[nt] = *(const s16x8*)&WuP[(((size_t)(wv * 8 + ncc * 4 + nt) * 8) + ks) * 512 + lane * 8];
            #pragma unroll
            for (int mt = 0; mt < 2; ++mt)
                #pragma unroll
                for (int nt = 0; nt < 4; ++nt)
                    c2[mt][nt] = __builtin_amdgcn_mfma_f32_16x16x32_bf16(af[mt], bfr[nt], c2[mt][nt], 0, 0, 0);
        }
        // bias at fragment mapping
        float bu_l[4];
        #pragma unroll
        for (int nt = 0; nt < 4; ++nt)
            bu_l[nt] = bup[cb + nt * 16 + l15];
        // per 16x64 tile: stage c2+bias; owning lanes add register residual, store
        #pragma unroll
        for (int mt = 0; mt < 2; ++mt) {
            #pragma unroll
            for (int nt = 0; nt < 4; ++nt)
                #pragma unroll
                for (int rr = 0; rr < 4; ++rr)
                    ep[wv][q * 4 + rr][nt * 16 + l15] = c2[mt][nt][rr] + bu_l[nt];
            __builtin_amdgcn_s_waitcnt(0xc07f);   // lgkmcnt(0): wave-local LDS drain
            // lanes whose (row, col-half) matches this tile: 16 lanes, each stores
            // its full row span: 64 floats = 256B contiguous, plain stores (L2 combines)
            if (half == ncc && (rowl >> 4) == mt) {
                float* orow = out + (row0 + rowl) * HID + cb;
                const int lr = rowl & 15;
                #pragma unroll
                for (int j = 0; j < 16; ++j) {
                    f32x4 v = *(const f32x4*)&ep[wv][lr][j * 4];
                    v += xreg[j];
                    *(f32x4*)(orow + j * 4) = v;
                }
            }
            __builtin_amdgcn_s_waitcnt(0xc07f);   // drain reads before next tile overwrites
        }
    }
}

extern "C" void kernel_launch(void* const* d_in, const int* in_sizes, int n_in,
                              void* d_out, int out_size, void* d_ws, size_t ws_size,
                              hipStream_t stream) {
    const float* x   = (const float*)d_in[0];
    const float* lnw = (const float*)d_in[1];
    const float* lnb = (const float*)d_in[2];
    const float* wd  = (const float*)d_in[3];
    const float* bd  = (const float*)d_in[4];
    const float* wu  = (const float*)d_in[5];
    const float* bu  = (const float*)d_in[6];
    float* out = (float*)d_out;

    unsigned short* WdP = (unsigned short*)d_ws;        // packed wd (lnw folded), 512KB
    unsigned short* WuP = WdP + (size_t)HID * ADP;      // packed wu, 512KB
    float* svec = (float*)(WuP + (size_t)HID * ADP);    // [256]
    float* tvec = svec + ADP;                           // [256]

    prep<<<257, 256, 0, stream>>>(wd, wu, lnw, lnb, bd, WdP, WuP, svec, tvec);

    const int rows = in_sizes[0] / HID;                 // 32768
    adapter_fused<<<rows / MB, 512, 0, stream>>>(x, bu, svec, tvec, WdP, WuP, out);
}

// Round 8
// 430.581 us; speedup vs baseline: 1.1383x; 1.1383x over previous
//
#include <hip/hip_runtime.h>

#define HID 1024
#define ADP 256
#define MB  32

typedef short s16x8 __attribute__((ext_vector_type(8)));
typedef unsigned short u16x8 __attribute__((ext_vector_type(8)));
typedef float f32x4 __attribute__((ext_vector_type(4)));

__device__ __forceinline__ unsigned short f2bf(float f) {
    union { float f; unsigned int u; } v; v.f = f;
    unsigned int r = v.u + 0x7fffu + ((v.u >> 16) & 1u);   // round-to-nearest-even
    return (unsigned short)(r >> 16);
}

__device__ __forceinline__ float bf2f(unsigned short u) {
    union { unsigned int u; float f; } v; v.u = ((unsigned int)u) << 16;
    return v.f;
}

__device__ __forceinline__ float gelu_new_f(float x) {
    float t = 0.7978845608028654f * x * (1.0f + 0.044715f * x * x);
    t = fminf(fmaxf(t, -15.f), 15.f);
    float e = __expf(-2.0f * t);
    float th = (1.0f - e) / (1.0f + e);
    return 0.5f * x * (1.0f + th);
}

// Single prep kernel:
//   blocks 0..127   : pack wd [1024][256] -> WdP fragment tiles (lnw folded)
//   blocks 128..255 : pack wu [256][1024] -> WuP fragment tiles
//   block 256       : svec/tvec correction vectors (coalesced over columns)
// Tile (nti,kti): 1KB, offset (q*16+l15)*8+e = W[kti*32+q*8+e][nti*16+l15]*scale.
__global__ __launch_bounds__(256)
void prep(const float* __restrict__ wd, const float* __restrict__ wu,
          const float* __restrict__ lnw, const float* __restrict__ lnb,
          const float* __restrict__ bdn,
          unsigned short* __restrict__ WdP, unsigned short* __restrict__ WuP,
          float* __restrict__ svec, float* __restrict__ tvec)
{
    __shared__ unsigned short sh[32][72];
    const int b = blockIdx.x, t = threadIdx.x;
    if (b < 256) {
        const float* in; unsigned short* outp; const float* scale; int K, N, kb, nb;
        if (b < 128) { in = wd; outp = WdP; scale = lnw; K = HID; N = ADP; kb = b & 31; nb = b >> 5; }
        else { int i = b - 128; in = wu; outp = WuP; scale = nullptr; K = ADP; N = HID; kb = i & 7; nb = i >> 3; }
        const int k0 = kb * 32, n0 = nb * 64;
        const int r = t >> 3, cg = t & 7;
        const float* src = in + (size_t)(k0 + r) * N + n0 + cg * 8;
        float sc = scale ? scale[k0 + r] : 1.0f;
        f32x4 v0 = *(const f32x4*)(src);
        f32x4 v1 = *(const f32x4*)(src + 4);
        #pragma unroll
        for (int e = 0; e < 4; ++e) {
            sh[r][cg * 8 + e]     = f2bf(sc * v0[e]);
            sh[r][cg * 8 + 4 + e] = f2bf(sc * v1[e]);
        }
        __syncthreads();
        int tile = t >> 6, l = t & 63, q = l >> 4, l15 = l & 15;
        u16x8 o;
        #pragma unroll
        for (int e = 0; e < 8; ++e)
            o[e] = sh[q * 8 + e][tile * 16 + l15];
        size_t tid_g = (size_t)(nb * 4 + tile) * (K / 32) + kb;
        *(u16x8*)(outp + tid_g * 512 + (size_t)l * 8) = o;
    } else {
        // corr: thread t = column a; coalesced row-major reads of wd
        float sv = 0.f, tv = 0.f;
        #pragma unroll 8
        for (int h = 0; h < HID; ++h) {
            float w = wd[(size_t)h * ADP + t];
            sv += bf2f(f2bf(lnw[h] * w));
            tv += lnb[h] * w;
        }
        svec[t] = sv;
        tvec[t] = bdn[t] + tv;
    }
}

__global__ __launch_bounds__(512, 2)   // 2 blk/CU * 8 waves = 4 waves/SIMD -> 128 VGPR cap (xreg must NOT spill)
void adapter_fused(const float* __restrict__ x,
                   const float* __restrict__ bup,
                   const float* __restrict__ svec, const float* __restrict__ tvec,
                   const unsigned short* __restrict__ WdP,   // packed [16 nti][32 kti]
                   const unsigned short* __restrict__ WuP,   // packed [64 nti][8 kti]
                   float* __restrict__ out)
{
    __shared__ unsigned short a_h[2][MB][264];  // double-buffered x chunk / h
    __shared__ float ep[8][16][68];             // per-wave epilogue staging (16x64)
    __shared__ float stats_part[MB][16];        // per-wave partial sums (s1,s2 interleaved)
    __shared__ float stats[MB][2];              // mean, rstd
    __shared__ float sv_s[ADP], tv_s[ADP];

    const int tid  = threadIdx.x;
    const int wv   = tid >> 6;                 // 8 waves
    const int lane = tid & 63;
    const int q    = lane >> 4;
    const int l15  = lane & 15;
    const long row0 = (long)blockIdx.x * MB;

    if (tid < ADP) { sv_s[tid] = svec[tid]; tv_s[tid] = tvec[tid]; }

    // ---- register slab: wave wv owns cols [wv*128, wv*128+128) of all 32 rows ----
    const int rowl = lane & 31;                // this lane's row
    const int half = lane >> 5;                // 0/1: which 64-col half of the slab
    const int gcol = wv * 128 + half * 64;     // lane's first global column

    f32x4 xreg[16];                            // 64 floats of x (fp32), 64 VGPRs
    {
        const f32x4* xr = (const f32x4*)(x + (row0 + rowl) * HID + gcol);
        #pragma unroll
        for (int i = 0; i < 16; ++i)
            xreg[i] = __builtin_nontemporal_load(&xr[i]);
    }

    f32x4 c1[2][2];
    #pragma unroll
    for (int a = 0; a < 2; ++a)
        #pragma unroll
        for (int bb = 0; bb < 2; ++bb)
            c1[a][bb] = (f32x4){0.f, 0.f, 0.f, 0.f};

    // stage this wave's slab (bf16) into a_h[buf] chunk (kc = wv>>1) + LN partial sums
    const int colb = (wv & 1) * 128 + half * 64;   // column offset within the 256-col chunk
    auto stage = [&](int buf) {
        float s1 = 0.f, s2 = 0.f;
        #pragma unroll
        for (int i = 0; i < 16; ++i) {
            f32x4 v = xreg[i];
            s1 += v[0] + v[1] + v[2] + v[3];
            s2 += v[0] * v[0] + v[1] * v[1] + v[2] * v[2] + v[3] * v[3];
            ushort4 o;
            o.x = f2bf(v[0]); o.y = f2bf(v[1]); o.z = f2bf(v[2]); o.w = f2bf(v[3]);
            *(ushort4*)&a_h[buf][rowl][colb + i * 4] = o;
        }
        s1 += __shfl_xor(s1, 32);
        s2 += __shfl_xor(s2, 32);
        if (lane < 32) {
            stats_part[rowl][wv * 2]     = s1;
            stats_part[rowl][wv * 2 + 1] = s2;
        }
    };

    if (wv < 2) stage(0);
    __syncthreads();

    // ---- GEMM1: c1 += bf16(x) * WdP, K-chunked with dbuf; owners stage next chunk ----
    for (int kc = 0; kc < 4; ++kc) {
        if (kc < 3 && (wv >> 1) == kc + 1) stage((kc + 1) & 1);
        const int buf = kc & 1;
        #pragma unroll
        for (int ks = 0; ks < 8; ++ks) {
            int kof = ks * 32 + q * 8;
            s16x8 af[2], bfr[2];
            af[0] = *(const s16x8*)&a_h[buf][l15][kof];
            af[1] = *(const s16x8*)&a_h[buf][16 + l15][kof];
            #pragma unroll
            for (int nt = 0; nt < 2; ++nt)
                bfr[nt] = *(const s16x8*)&WdP[(((size_t)(wv * 2 + nt) * 32) + kc * 8 + ks) * 512 + lane * 8];
            #pragma unroll
            for (int mt = 0; mt < 2; ++mt)
                #pragma unroll
                for (int nt = 0; nt < 2; ++nt)
                    c1[mt][nt] = __builtin_amdgcn_mfma_f32_16x16x32_bf16(af[mt], bfr[nt], c1[mt][nt], 0, 0, 0);
        }
        __syncthreads();
    }

    // ---- finalize LN statistics (reduce 8 per-wave partials per row) ----
    if (tid < 32) {
        float s1 = 0.f, s2 = 0.f;
        #pragma unroll
        for (int w = 0; w < 8; ++w) {
            s1 += stats_part[tid][w * 2];
            s2 += stats_part[tid][w * 2 + 1];
        }
        float mean = s1 * (1.f / HID);
        float var  = s2 * (1.f / HID) - mean * mean;
        stats[tid][0] = mean;
        stats[tid][1] = rsqrtf(var + 1e-5f);
    }
    __syncthreads();

    // ---- LN correction + gelu -> bf16 h in a_h[0] (viewed [32][264], 256 cols used) ----
    #pragma unroll
    for (int mt = 0; mt < 2; ++mt)
        #pragma unroll
        for (int nt = 0; nt < 2; ++nt) {
            int a = wv * 32 + nt * 16 + l15;
            float sv = sv_s[a], tv = tv_s[a];
            #pragma unroll
            for (int rr = 0; rr < 4; ++rr) {
                int m = mt * 16 + q * 4 + rr;
                float mean = stats[m][0], rstd = stats[m][1];
                float c = rstd * (c1[mt][nt][rr] - mean * sv) + tv;
                a_h[0][m][a] = f2bf(gelu_new_f(c));
            }
        }
    __syncthreads();

    // ---- GEMM2 + epilogue: wave wv produces cols [wv*128, +128) = its x slab ----
    for (int ncc = 0; ncc < 2; ++ncc) {
        const int cb = wv * 128 + ncc * 64;
        f32x4 c2[2][4];
        #pragma unroll
        for (int a = 0; a < 2; ++a)
            #pragma unroll
            for (int bb = 0; bb < 4; ++bb)
                c2[a][bb] = (f32x4){0.f, 0.f, 0.f, 0.f};
        #pragma unroll
        for (int ks = 0; ks < 8; ++ks) {
            int kof = ks * 32 + q * 8;
            s16x8 af[2], bfr[4];
            af[0] = *(const s16x8*)&a_h[0][l15][kof];
            af[1] = *(const s16x8*)&a_h[0][16 + l15][kof];
            #pragma unroll
            for (int nt = 0; nt < 4; ++nt)
                bfr[nt] = *(const s16x8*)&WuP[(((size_t)(wv * 8 + ncc * 4 + nt) * 8) + ks) * 512 + lane * 8];
            #pragma unroll
            for (int mt = 0; mt < 2; ++mt)
                #pragma unroll
                for (int nt = 0; nt < 4; ++nt)
                    c2[mt][nt] = __builtin_amdgcn_mfma_f32_16x16x32_bf16(af[mt], bfr[nt], c2[mt][nt], 0, 0, 0);
        }
        // bias at fragment mapping
        float bu_l[4];
        #pragma unroll
        for (int nt = 0; nt < 4; ++nt)
            bu_l[nt] = bup[cb + nt * 16 + l15];
        // per 16x64 tile: stage c2+bias; owning lanes add register residual, store
        #pragma unroll
        for (int mt = 0; mt < 2; ++mt) {
            #pragma unroll
            for (int nt = 0; nt < 4; ++nt)
                #pragma unroll
                for (int rr = 0; rr < 4; ++rr)
                    ep[wv][q * 4 + rr][nt * 16 + l15] = c2[mt][nt][rr] + bu_l[nt];
            __builtin_amdgcn_s_waitcnt(0xc07f);   // lgkmcnt(0): wave-local LDS drain
            // lanes whose (row, col-half) matches this tile: 16 lanes, each stores
            // its full row span: 64 floats = 256B contiguous, plain stores (L2 combines)
            if (half == ncc && (rowl >> 4) == mt) {
                float* orow = out + (row0 + rowl) * HID + cb;
                const int lr = rowl & 15;
                #pragma unroll
                for (int j = 0; j < 16; ++j) {
                    f32x4 v = *(const f32x4*)&ep[wv][lr][j * 4];
                    v += xreg[j];
                    *(f32x4*)(orow + j * 4) = v;
                }
            }
            __builtin_amdgcn_s_waitcnt(0xc07f);   // drain reads before next tile overwrites
        }
    }
}

extern "C" void kernel_launch(void* const* d_in, const int* in_sizes, int n_in,
                              void* d_out, int out_size, void* d_ws, size_t ws_size,
                              hipStream_t stream) {
    const float* x   = (const float*)d_in[0];
    const float* lnw = (const float*)d_in[1];
    const float* lnb = (const float*)d_in[2];
    const float* wd  = (const float*)d_in[3];
    const float* bd  = (const float*)d_in[4];
    const float* wu  = (const float*)d_in[5];
    const float* bu  = (const float*)d_in[6];
    float* out = (float*)d_out;

    unsigned short* WdP = (unsigned short*)d_ws;        // packed wd (lnw folded), 512KB
    unsigned short* WuP = WdP + (size_t)HID * ADP;      // packed wu, 512KB
    float* svec = (float*)(WuP + (size_t)HID * ADP);    // [256]
    float* tvec = svec + ADP;                           // [256]

    prep<<<257, 256, 0, stream>>>(wd, wu, lnw, lnb, bd, WdP, WuP, svec, tvec);

    const int rows = in_sizes[0] / HID;                 // 32768
    adapter_fused<<<rows / MB, 512, 0, stream>>>(x, bu, svec, tvec, WdP, WuP, out);
}